// Round 18
// baseline (95.925 us; speedup 1.0000x reference)
//
#include <hip/hip_runtime.h>
#include <cstddef>
#include <cstdint>

#define LEAKY(s) ((s) >= 0.f ? (s) : 0.1f * (s))

constexpr int PTS    = 4096;   // H*W
constexpr int NBATCH = 32;
constexpr int NM     = 8;      // regions
constexpr int TILE   = 128;    // points per block in kA
constexpr int NTILES = PTS / TILE;  // 32

// ---------------- workspace layout (bytes) ----------------
constexpr size_t OFF_POOL = 0;        // pool (B,1024) u32 (enc f32) 128KB
constexpr size_t OFF_WSP  = 131072;   // bf16 weights: w1pad(8KB) w2(32KB) w3(32KB)
constexpr size_t OFF_Y32  = 262144;   // y32 (B,32,1024) f32 4MB
constexpr size_t OFF_Y    = 4456448;  // y (B,1024) f32 128KB
constexpr size_t OFF_H1   = 4587520;  // h1 (B,512) f32 64KB

using bf16x8 = __attribute__((ext_vector_type(8))) short;
using f32x4v = __attribute__((ext_vector_type(4))) float;
using u16x4  = __attribute__((ext_vector_type(4))) unsigned short;
using u16x8  = __attribute__((ext_vector_type(8))) unsigned short;

// RNE round f32 -> bf16
__device__ __forceinline__ unsigned short rbf(float x) {
  unsigned u = __float_as_uint(x);
  return (unsigned short)((u + 0x7FFFu + ((u >> 16) & 1u)) >> 16);
}

// monotone f32 <-> u32 encoding (order-preserving) for atomicMax pooling
__device__ __forceinline__ unsigned encf(float f) {
  unsigned u = __float_as_uint(f);
  return (u & 0x80000000u) ? ~u : (u | 0x80000000u);
}
__device__ __forceinline__ float decf(unsigned e) {
  unsigned u = (e & 0x80000000u) ? (e ^ 0x80000000u) : ~u * 0 + ~e;
  return __uint_as_float((e & 0x80000000u) ? (e ^ 0x80000000u) : ~e);
}

// swizzled byte offset into Xt[pt][k] bf16 array (row = 256B): XOR bits 4..6 by pt&7
__device__ __forceinline__ int swzb(int pt, int kByte) {
  return pt * 256 + (kByte ^ ((pt & 7) << 4));
}

// ============================================================
// Kernel W: prep bf16 weight planes + zero pool. grid(128),256.
// wsp: [w1pad 4096 u16][w2 16384 u16][w3 16384 u16]
// ============================================================
__global__ __launch_bounds__(256) void kW(const float* __restrict__ w1,
                                          const float* __restrict__ w2,
                                          const float* __restrict__ w3,
                                          unsigned short* __restrict__ wsp,
                                          unsigned* __restrict__ pool) {
  int id = blockIdx.x * 256 + threadIdx.x;   // 0..32767
  pool[id] = 0u;                             // enc(x) > 0 for all finite x
  {  // w2/w3
    int layer = id >> 14, e16 = id & 16383;
    int e = e16 & 7, l15 = (e16 >> 3) & 15, l4 = (e16 >> 7) & 3,
        kt = (e16 >> 9) & 3, mt = e16 >> 11;
    int c = mt * 16 + l15, k = kt * 32 + l4 * 8 + e;
    float v = (layer ? w3 : w2)[c * 128 + k];
    wsp[4096 + layer * 16384 + e16] = rbf(v);
  }
  if (id < 4096) {  // w1pad
    int e = id & 7, l15 = (id >> 3) & 15, l4 = (id >> 7) & 3, mt = id >> 9;
    int c = mt * 16 + l15, k = l4 * 8 + e;
    wsp[id] = (k < 5) ? rbf(w1[c * 5 + k]) : (unsigned short)0;
  }
}

// ============================================================
// Kernel A: conv1 (MFMA, padded K=32) -> conv2 -> conv3 (bf16 MFMA) ->
// masked-max -> atomicMax pool. grid (NTILES=32, B), 512 thr / 8 waves,
// 40KB LDS -> 4 blocks/CU (8 waves/SIMD). Region read from global in
// epilogue (L2-hot, exact f32) -- no reg_s.
// ============================================================
__device__ __forceinline__ void mfmaLayer8s(const unsigned short* __restrict__ W,
                                            const float* __restrict__ bias,
                                            const char* Xc,
                                            int lane, int mt, f32x4v acc[8]) {
  const int l15 = lane & 15, l4 = lane >> 4;
  {
    float4 bv = *(const float4*)(bias + mt * 16 + l4 * 4);
    f32x4v b4; b4[0] = bv.x; b4[1] = bv.y; b4[2] = bv.z; b4[3] = bv.w;
#pragma unroll
    for (int nt = 0; nt < 8; nt++) acc[nt] = b4;
  }
#pragma unroll
  for (int kt = 0; kt < 4; kt++) {
    int woff = (((mt * 4 + kt) * 4 + l4) * 16 + l15) * 8;
    bf16x8 ah = *(const bf16x8*)(W + woff);
    const int kb = (kt * 32 + l4 * 8) * 2;
#pragma unroll
    for (int nt = 0; nt < 8; nt++) {
      bf16x8 bh = *(const bf16x8*)(Xc + swzb(nt * 16 + l15, kb));
      acc[nt] = __builtin_amdgcn_mfma_f32_16x16x32_bf16(ah, bh, acc[nt], 0, 0, 0);
    }
  }
}

__global__ __launch_bounds__(512, 8) void kA(
    const float* __restrict__ coor, const float* __restrict__ region,
    const float* __restrict__ extents,
    const float* __restrict__ b1, const float* __restrict__ b2,
    const float* __restrict__ b3,
    const unsigned short* __restrict__ wsp,
    unsigned* __restrict__ pool) {
  __shared__ unsigned short X[128 * 128];   // 32KB bf16 acts (f32 funnel aliases)
  __shared__ unsigned short X5[128 * 32];   // 8KB input plane, row stride 64B
  const int tid = threadIdx.x;
  const int b = blockIdx.y;
  const int t0 = blockIdx.x * TILE;
  const int lane = tid & 63;
  const int wv = tid >> 6;                  // 0..7
  char* Xc = (char*)X;
  char* X5c = (char*)X5;

  {  // stage input plane X5[pt][k<32] bf16 (zeros for k>=5)
    const int pt = tid & 127;
    const int part = tid >> 7;  // 0..3 -> 16B chunk
    u16x8 hh = {0, 0, 0, 0, 0, 0, 0, 0};
    if (part == 0) {
      float e0 = extents[b * 3], e1 = extents[b * 3 + 1], e2 = extents[b * 3 + 2];
      float in5[5];
#pragma unroll
      for (int i = 0; i < 5; i++) in5[i] = coor[((size_t)b * 5 + i) * PTS + t0 + pt];
      in5[0] = (in5[0] - 0.5f) * e0;
      in5[1] = (in5[1] - 0.5f) * e1;
      in5[2] = (in5[2] - 0.5f) * e2;
#pragma unroll
      for (int q = 0; q < 5; q++) hh[q] = rbf(in5[q]);
    }
    *(u16x8*)(X5c + pt * 64 + part * 16) = hh;
  }
  __syncthreads();

  f32x4v acc[8];
  const int mt = wv;
  const int l15 = lane & 15, l4 = lane >> 4;

  {  // layer 1: single MFMA k-step (K=32, zero-padded)
    float4 bv = *(const float4*)(b1 + mt * 16 + l4 * 4);
    f32x4v b4; b4[0] = bv.x; b4[1] = bv.y; b4[2] = bv.z; b4[3] = bv.w;
#pragma unroll
    for (int nt = 0; nt < 8; nt++) acc[nt] = b4;
    bf16x8 ah = *(const bf16x8*)(wsp + ((mt * 4 + l4) * 16 + l15) * 8);
#pragma unroll
    for (int nt = 0; nt < 8; nt++) {
      bf16x8 bh = *(const bf16x8*)(X5c + (nt * 16 + l15) * 64 + l4 * 16);
      acc[nt] = __builtin_amdgcn_mfma_f32_16x16x32_bf16(ah, bh, acc[nt], 0, 0, 0);
    }
  }
  {  // leaky + round + write act1 to X
    const int ch0 = mt * 16 + l4 * 4;
#pragma unroll
    for (int nt = 0; nt < 8; nt++) {
      u16x4 h4;
#pragma unroll
      for (int r = 0; r < 4; r++) {
        float s = acc[nt][r];
        s = LEAKY(s);
        h4[r] = rbf(s);
      }
      int off = swzb(nt * 16 + l15, ch0 * 2);
      *(u16x4*)(Xc + off) = h4;
    }
  }
  __syncthreads();

  // layer 2
  mfmaLayer8s(wsp + 4096, b2, Xc, lane, mt, acc);
  __syncthreads();
  {  // leaky + round + write act2 back to X
    const int ch0 = mt * 16 + l4 * 4;
#pragma unroll
    for (int nt = 0; nt < 8; nt++) {
      u16x4 h4;
#pragma unroll
      for (int r = 0; r < 4; r++) {
        float s = acc[nt][r];
        s = LEAKY(s);
        h4[r] = rbf(s);
      }
      int off = swzb(nt * 16 + l15, ch0 * 2);
      *(u16x4*)(Xc + off) = h4;
    }
  }
  __syncthreads();
  // layer 3 (bias, no activation)
  mfmaLayer8s(wsp + 20480, b3, Xc, lane, mt, acc);
  __syncthreads();  // all X reads done; reuse X as f32 funnel

  {  // region-masked max -> funnel[c*8+m]; region from global (L2-hot, f32)
    float* funnel = (float*)X;
#pragma unroll
    for (int m = 0; m < NM; m++) {
      const float* rp = region + ((size_t)b * NM + m) * PTS + t0 + l15;
      float rv[8];
#pragma unroll
      for (int nt = 0; nt < 8; nt++) rv[nt] = rp[nt * 16];
#pragma unroll
      for (int r = 0; r < 4; r++) {
        float mx = acc[0][r] * rv[0];
#pragma unroll
        for (int nt = 1; nt < 8; nt++) mx = fmaxf(mx, acc[nt][r] * rv[nt]);
        mx = fmaxf(mx, __shfl_xor(mx, 1));
        mx = fmaxf(mx, __shfl_xor(mx, 2));
        mx = fmaxf(mx, __shfl_xor(mx, 4));
        mx = fmaxf(mx, __shfl_xor(mx, 8));
        if (l15 == 0) funnel[(mt * 16 + l4 * 4 + r) * 8 + m] = mx;
      }
    }
  }
  __syncthreads();
  {  // order-independent pool: atomicMax of monotone-encoded f32 (2/thread)
    const float* fun = (const float*)X;
    unsigned* pl = pool + (size_t)b * 1024;
    atomicMax(pl + tid, encf(fun[tid]));
    atomicMax(pl + tid + 512, encf(fun[tid + 512]));
  }
}

// ============================================================
// Kernel C (o-split + fused softmax/sort): grid(512) 1-D, XCD-aware.
// id -> kt = (id&7)|((id>>7)<<3), bg = (id>>3)&7, og2 = (id>>6)&1.
// Block: 4 k x 64 o x 4 b x 8 m. As[16][260] + xsl 16KB -> 4 blocks/CU.
// ============================================================
__global__ __launch_bounds__(256) void kC(const unsigned* __restrict__ pool,
                                          const float* __restrict__ w_sp,
                                          float* __restrict__ y32) {
  __shared__ float As[16 * 260];     // 16.6KB [cc][row = kk*64 + o', pad 4]
  __shared__ float xsl[4 * 128 * 8]; // 16KB  [bl][c][m]
  __shared__ int idxL[4][4][8];      // [bl][kk][r]
  const int tid = threadIdx.x;
  const int id = blockIdx.x;
  const int kt = (id & 7) | ((id >> 7) << 3);   // 0..31, same-kt -> same XCD
  const int bg = (id >> 3) & 7;                 // 0..7
  const int og2 = (id >> 6) & 1;                // 0..1
  const int k0 = kt * 4;
  const int o0 = og2 * 64;
  const int bbase = bg * 4;
  const int rg = tid & 63, cgq = tid >> 6;

  // decode pool (4 b x 1024) -> xsl
#pragma unroll
  for (int it = 0; it < 4; it++) {
    uint4 v = *(const uint4*)(pool + (size_t)(bbase + it) * 1024 + tid * 4);
    float4 f = {decf(v.x), decf(v.y), decf(v.z), decf(v.w)};
    *(float4*)(xsl + it * 1024 + tid * 4) = f;
  }
  // prologue: issue c0=0 staging loads (float4 = 4 k values)
  float4 wreg[4];
#pragma unroll
  for (int it = 0; it < 4; it++) {
    int q = tid + it * 256, o = q >> 4, cc = q & 15;
    wreg[it] = *(const float4*)(w_sp + (size_t)(o0 + o) * 16384 + (size_t)cc * 128 + k0);
  }
  __syncthreads();
  {  // softmax over c per (bl, m): 32 pairs x 8 threads
    int pair = tid >> 3, sub = tid & 7;
    int bl = pair >> 3, m = pair & 7;
    float* base = xsl + bl * 1024 + m;
    float v[16];
#pragma unroll
    for (int j = 0; j < 16; j++) v[j] = base[(sub + 8 * j) * 8];
    float mx = v[0];
#pragma unroll
    for (int j = 1; j < 16; j++) mx = fmaxf(mx, v[j]);
    mx = fmaxf(mx, __shfl_xor(mx, 1));
    mx = fmaxf(mx, __shfl_xor(mx, 2));
    mx = fmaxf(mx, __shfl_xor(mx, 4));
    float s = 0.f;
#pragma unroll
    for (int j = 0; j < 16; j++) { v[j] = expf(v[j] - mx); s += v[j]; }
    s += __shfl_xor(s, 1);
    s += __shfl_xor(s, 2);
    s += __shfl_xor(s, 4);
    float inv = 1.f / s;
#pragma unroll
    for (int j = 0; j < 16; j++) base[(sub + 8 * j) * 8] = v[j] * inv;
  }
  __syncthreads();
  if (tid < 16) {  // sort this block's 4 k-channels per batch
    int bl = tid >> 2, kk = tid & 3;
    float vv[8];
#pragma unroll
    for (int n = 0; n < 8; n++) vv[n] = xsl[bl * 1024 + (k0 + kk) * 8 + n];
    int used = 0;
#pragma unroll
    for (int n = 0; n < 8; n++) {
      int best = 0; float bv = -1.f;
#pragma unroll
      for (int q = 0; q < 8; q++) {
        bool ok = ((used >> q) & 1) == 0;
        if (ok && vv[q] > bv) { bv = vv[q]; best = q; }  // strict > == lowest-index tie-break
      }
      used |= 1 << best;
      idxL[bl][kk][n] = best;
    }
  }

  float acc[4][8];
#pragma unroll
  for (int i = 0; i < 4; i++)
#pragma unroll
    for (int j = 0; j < 8; j++) acc[i][j] = 0.f;

  for (int c0 = 0; c0 < 128; c0 += 16) {
    __syncthreads();
#pragma unroll
    for (int it = 0; it < 4; it++) {
      int q = tid + it * 256, o = q >> 4, cc = q & 15;
      As[cc * 260 + o]       = wreg[it].x;   // kk=0
      As[cc * 260 + 64 + o]  = wreg[it].y;   // kk=1
      As[cc * 260 + 128 + o] = wreg[it].z;   // kk=2
      As[cc * 260 + 192 + o] = wreg[it].w;   // kk=3
    }
    __syncthreads();
    if (c0 + 16 < 128) {  // prefetch next chunk (hidden under compute)
#pragma unroll
      for (int it = 0; it < 4; it++) {
        int q = tid + it * 256, o = q >> 4, cc = q & 15;
        wreg[it] = *(const float4*)(w_sp + (size_t)(o0 + o) * 16384 + (size_t)(c0 + 16 + cc) * 128 + k0);
      }
    }
#pragma unroll
    for (int cc = 0; cc < 16; cc++) {
      float4 a = *(const float4*)(As + cc * 260 + rg * 4);
      float4 p0 = *(const float4*)(xsl + cgq * 1024 + (c0 + cc) * 8);      // broadcast
      float4 p1 = *(const float4*)(xsl + cgq * 1024 + (c0 + cc) * 8 + 4);  // broadcast
      float av[4] = {a.x, a.y, a.z, a.w};
      float bv[8] = {p0.x, p0.y, p0.z, p0.w, p1.x, p1.y, p1.z, p1.w};
#pragma unroll
      for (int i = 0; i < 4; i++)
#pragma unroll
        for (int j = 0; j < 8; j++) acc[i][j] = fmaf(av[i], bv[j], acc[i][j]);
    }
  }
  // gather-sum epilogue: row = rg*4+i -> kk = rg>>4, o' = row&63.
  const int kk = rg >> 4;
  int ms[8];
#pragma unroll
  for (int r = 0; r < 8; r++) ms[r] = idxL[cgq][kk][r];
  float yp[4][8];
#pragma unroll
  for (int i4 = 0; i4 < 4; i4++) {
#pragma unroll
    for (int r = 0; r < 8; r++) {
      float v = 0.f;
#pragma unroll
      for (int j = 0; j < 8; j++) v += (j == ms[r]) ? acc[i4][j] : 0.f;
      yp[i4][r] = v;
    }
  }
#pragma unroll
  for (int i4 = 0; i4 < 4; i4++)
#pragma unroll
    for (int r = 0; r < 8; r++) {
      yp[i4][r] += __shfl_xor(yp[i4][r], 16);
      yp[i4][r] += __shfl_xor(yp[i4][r], 32);
    }
  if (rg < 16) {  // lane rg: o' = rg*4 + i4
    float* dst = y32 + ((size_t)(bbase + cgq) * 32 + kt) * 1024 + (size_t)(o0 + rg * 4) * 8;
#pragma unroll
    for (int i4 = 0; i4 < 4; i4++) {
      float4 v0 = {yp[i4][0], yp[i4][1], yp[i4][2], yp[i4][3]};
      float4 v1 = {yp[i4][4], yp[i4][5], yp[i4][6], yp[i4][7]};
      *(float4*)(dst + i4 * 8) = v0;
      *(float4*)(dst + i4 * 8 + 4) = v1;
    }
  }
}

// ============================================================
// Kernel Y: y[b][f] = leaky(sum_t y32[b][t][f] + b_sp[f>>3]). grid (4, B).
// ============================================================
__global__ __launch_bounds__(256) void kY(const float* __restrict__ y32,
                                          const float* __restrict__ b_sp,
                                          float* __restrict__ y) {
  int fg = blockIdx.x, b = blockIdx.y, tid = threadIdx.x;
  int f = fg * 256 + tid;
  const float* base = y32 + (size_t)b * 32768 + f;
  float s = 0.f;
#pragma unroll 8
  for (int t = 0; t < 32; t++) s += base[t * 1024];
  s += b_sp[f >> 3];
  y[(size_t)b * 1024 + f] = LEAKY(s);
}

// ============================================================
// Kernel E1: fc1 -> h1. grid (8, B), 256 thr; wave-per-output, coalesced rows.
// ============================================================
__global__ __launch_bounds__(256) void kE1(
    const float* __restrict__ y, const float* __restrict__ fc1_w,
    const float* __restrict__ fc1_b, float* __restrict__ h1) {
  int og = blockIdx.x, b = blockIdx.y, tid = threadIdx.x;
  int wid = tid >> 6, lane = tid & 63;
  const float4* yv = (const float4*)(y + (size_t)b * 1024);
  float4 u[4];
#pragma unroll
  for (int r = 0; r < 4; r++) u[r] = yv[r * 64 + lane];
#pragma unroll 4
  for (int pass = 0; pass < 16; pass++) {
    int o = og * 64 + pass * 4 + wid;
    const float4* wr = (const float4*)(fc1_w + (size_t)o * 1024);
    float sa = 0, sb = 0, sc = 0, sd = 0;
#pragma unroll
    for (int r = 0; r < 4; r++) {
      float4 wv = wr[r * 64 + lane];
      sa = fmaf(wv.x, u[r].x, sa); sb = fmaf(wv.y, u[r].y, sb);
      sc = fmaf(wv.z, u[r].z, sc); sd = fmaf(wv.w, u[r].w, sd);
    }
    float s = (sa + sb) + (sc + sd);
#pragma unroll
    for (int d = 1; d < 64; d <<= 1) s += __shfl_xor(s, d);
    if (lane == 0) {
      float t = s + fc1_b[o];
      h1[(size_t)b * 512 + o] = LEAKY(t);
    }
  }
}

// ============================================================
// Kernel E2: fc2 -> heads. grid (B), 1024 thr (16 waves).
// ============================================================
__global__ __launch_bounds__(1024) void kE2(
    const float* __restrict__ h1, const float* __restrict__ fc2_w,
    const float* __restrict__ fc2_b,
    const float* __restrict__ fcr_w, const float* __restrict__ fcr_b,
    const float* __restrict__ fct_w, const float* __restrict__ fct_b,
    float* __restrict__ out) {
  __shared__ float h1l[512];
  __shared__ float h2[256];
  int b = blockIdx.x, tid = threadIdx.x;
  int w = tid >> 6, lane = tid & 63;
  if (tid < 128) {
    float4 v = ((const float4*)(h1 + (size_t)b * 512))[tid];
    ((float4*)h1l)[tid] = v;
  }
  __syncthreads();
  {  // fc2: 16 waves x 16 outputs, coalesced rows
    const float4* h1v = (const float4*)h1l;
    float4 u0 = h1v[lane], u1 = h1v[64 + lane];
#pragma unroll 2
    for (int pass = 0; pass < 16; pass++) {
      int o = w * 16 + pass;
      const float4* wr = (const float4*)(fc2_w + (size_t)o * 512);
      float4 w0 = wr[lane], w1 = wr[64 + lane];
      float sa = fmaf(w0.x, u0.x, 0.f), sb = fmaf(w0.y, u0.y, 0.f);
      float sc = fmaf(w0.z, u0.z, 0.f), sd = fmaf(w0.w, u0.w, 0.f);
      sa = fmaf(w1.x, u1.x, sa); sb = fmaf(w1.y, u1.y, sb);
      sc = fmaf(w1.z, u1.z, sc); sd = fmaf(w1.w, u1.w, sd);
      float s = (sa + sb) + (sc + sd);
#pragma unroll
      for (int d = 1; d < 64; d <<= 1) s += __shfl_xor(s, d);
      if (lane == 0) {
        float t = s + fc2_b[o];
        h2[o] = LEAKY(t);
      }
    }
  }
  __syncthreads();
  if (w < 7) {  // heads: wave-per-output
    bool isrot = w < 4;
    int o = isrot ? w : w - 4;
    const float4* wr = (const float4*)((isrot ? fcr_w : fct_w) + (size_t)o * 256);
    const float4* uv = (const float4*)h2;
    float4 wv = wr[lane];
    float4 u = uv[lane];
    float s = fmaf(wv.x, u.x, fmaf(wv.y, u.y, fmaf(wv.z, u.z, wv.w * u.w)));
#pragma unroll
    for (int d = 1; d < 64; d <<= 1) s += __shfl_xor(s, d);
    if (lane == 0) {
      float t = s + (isrot ? fcr_b[o] : fct_b[o]);
      out[isrot ? (b * 4 + o) : (128 + b * 3 + o)] = t;
    }
  }
}

extern "C" void kernel_launch(void* const* d_in, const int* in_sizes, int n_in,
                              void* d_out, int out_size, void* d_ws, size_t ws_size,
                              hipStream_t stream) {
  const float* coor    = (const float*)d_in[0];
  const float* region  = (const float*)d_in[1];
  const float* extents = (const float*)d_in[2];
  const float* w1 = (const float*)d_in[3];  const float* b1 = (const float*)d_in[4];
  const float* w2 = (const float*)d_in[5];  const float* b2 = (const float*)d_in[6];
  const float* w3 = (const float*)d_in[7];  const float* b3 = (const float*)d_in[8];
  const float* w_sp = (const float*)d_in[9];  const float* b_sp = (const float*)d_in[10];
  const float* fc1_w = (const float*)d_in[11]; const float* fc1_b = (const float*)d_in[12];
  const float* fc2_w = (const float*)d_in[13]; const float* fc2_b = (const float*)d_in[14];
  const float* fcr_w = (const float*)d_in[15]; const float* fcr_b = (const float*)d_in[16];
  const float* fct_w = (const float*)d_in[17]; const float* fct_b = (const float*)d_in[18];

  char* ws = (char*)d_ws;
  unsigned* pool = (unsigned*)(ws + OFF_POOL);
  unsigned short* wsp = (unsigned short*)(ws + OFF_WSP);
  float* y32  = (float*)(ws + OFF_Y32);
  float* y    = (float*)(ws + OFF_Y);
  float* h1   = (float*)(ws + OFF_H1);
  float* out  = (float*)d_out;

  kW<<<dim3(128), 256, 0, stream>>>(w1, w2, w3, wsp, pool);
  kA<<<dim3(NTILES, NBATCH), 512, 0, stream>>>(coor, region, extents,
                                               b1, b2, b3, wsp, pool);
  kC<<<dim3(512), 256, 0, stream>>>(pool, w_sp, y32);
  kY<<<dim3(4, NBATCH), 256, 0, stream>>>(y32, b_sp, y);
  kE1<<<dim3(8, NBATCH), 256, 0, stream>>>(y, fc1_w, fc1_b, h1);
  kE2<<<dim3(NBATCH), 1024, 0, stream>>>(h1, fc2_w, fc2_b, fcr_w, fcr_b,
                                         fct_w, fct_b, out);
}

// Round 19
// 93.217 us; speedup vs baseline: 1.0290x; 1.0290x over previous
//
#include <hip/hip_runtime.h>
#include <cstddef>
#include <cstdint>

#define LEAKY(s) ((s) >= 0.f ? (s) : 0.1f * (s))

constexpr int PTS    = 4096;   // H*W
constexpr int NBATCH = 32;
constexpr int NM     = 8;      // regions
constexpr int TILE   = 128;    // points per block in kA
constexpr int NTILES = PTS / TILE;  // 32

// ---------------- workspace layout (bytes) ----------------
constexpr size_t OFF_POOL = 0;        // pool (B,1024) u32 (enc f32) 128KB
constexpr size_t OFF_WSP  = 131072;   // bf16 weights: w1pad(8KB) w2(32KB) w3(32KB)
constexpr size_t OFF_Y32  = 262144;   // y32 (B,32,1024) f32 4MB
constexpr size_t OFF_Y    = 4456448;  // y (B,1024) f32 128KB
constexpr size_t OFF_H1   = 4587520;  // h1 (B,512) f32 64KB

using bf16x8 = __attribute__((ext_vector_type(8))) short;
using f32x4v = __attribute__((ext_vector_type(4))) float;
using u16x4  = __attribute__((ext_vector_type(4))) unsigned short;
using u16x8  = __attribute__((ext_vector_type(8))) unsigned short;

// RNE round f32 -> bf16
__device__ __forceinline__ unsigned short rbf(float x) {
  unsigned u = __float_as_uint(x);
  return (unsigned short)((u + 0x7FFFu + ((u >> 16) & 1u)) >> 16);
}

// monotone f32 <-> u32 encoding (order-preserving) for atomicMax pooling
__device__ __forceinline__ unsigned encf(float f) {
  unsigned u = __float_as_uint(f);
  return (u & 0x80000000u) ? ~u : (u | 0x80000000u);
}
__device__ __forceinline__ float decf(unsigned e) {
  unsigned u = (e & 0x80000000u) ? (e ^ 0x80000000u) : ~e;
  return __uint_as_float(u);
}

// swizzled byte offset into Xt[pt][k] bf16 array (row = 256B): XOR bits 4..6 by pt&7
__device__ __forceinline__ int swzb(int pt, int kByte) {
  return pt * 256 + (kByte ^ ((pt & 7) << 4));
}

// ============================================================
// Kernel W: prep bf16 weight planes + zero pool. grid(128),256.
// wsp: [w1pad 4096 u16][w2 16384 u16][w3 16384 u16]
// w1pad elem = ((mt*4 + l4)*16 + l15)*8 + e ; c = mt*16+l15, k = l4*8+e (<5 else 0)
// w2/w3 elem = (((mt*4+kt)*4+l4)*16+l15)*8+e ; c=mt*16+l15, k=kt*32+l4*8+e
// ============================================================
__global__ __launch_bounds__(256) void kW(const float* __restrict__ w1,
                                          const float* __restrict__ w2,
                                          const float* __restrict__ w3,
                                          unsigned short* __restrict__ wsp,
                                          unsigned* __restrict__ pool) {
  int id = blockIdx.x * 256 + threadIdx.x;   // 0..32767
  pool[id] = 0u;                             // enc(x) > 0 for all finite x
  {  // w2/w3
    int layer = id >> 14, e16 = id & 16383;
    int e = e16 & 7, l15 = (e16 >> 3) & 15, l4 = (e16 >> 7) & 3,
        kt = (e16 >> 9) & 3, mt = e16 >> 11;
    int c = mt * 16 + l15, k = kt * 32 + l4 * 8 + e;
    float v = (layer ? w3 : w2)[c * 128 + k];
    wsp[4096 + layer * 16384 + e16] = rbf(v);
  }
  if (id < 4096) {  // w1pad
    int e = id & 7, l15 = (id >> 3) & 15, l4 = (id >> 7) & 3, mt = id >> 9;
    int c = mt * 16 + l15, k = l4 * 8 + e;
    wsp[id] = (k < 5) ? rbf(w1[c * 5 + k]) : (unsigned short)0;
  }
}

// ============================================================
// Kernel A: conv1 (MFMA, padded K=32) -> conv2 -> conv3 (bf16 MFMA) ->
// masked-max -> atomicMax pool. grid (NTILES=32, B), 512 thr / 8 waves,
// 47KB LDS -> 3 blocks/CU.
// ============================================================
__device__ __forceinline__ void mfmaLayer8s(const unsigned short* __restrict__ W,
                                            const float* __restrict__ bias,
                                            const char* Xc,
                                            int lane, int mt, f32x4v acc[8]) {
  const int l15 = lane & 15, l4 = lane >> 4;
  {
    float4 bv = *(const float4*)(bias + mt * 16 + l4 * 4);
    f32x4v b4; b4[0] = bv.x; b4[1] = bv.y; b4[2] = bv.z; b4[3] = bv.w;
#pragma unroll
    for (int nt = 0; nt < 8; nt++) acc[nt] = b4;
  }
#pragma unroll
  for (int kt = 0; kt < 4; kt++) {
    int woff = (((mt * 4 + kt) * 4 + l4) * 16 + l15) * 8;
    bf16x8 ah = *(const bf16x8*)(W + woff);
    const int kb = (kt * 32 + l4 * 8) * 2;
#pragma unroll
    for (int nt = 0; nt < 8; nt++) {
      bf16x8 bh = *(const bf16x8*)(Xc + swzb(nt * 16 + l15, kb));
      acc[nt] = __builtin_amdgcn_mfma_f32_16x16x32_bf16(ah, bh, acc[nt], 0, 0, 0);
    }
  }
}

__global__ __launch_bounds__(512, 6) void kA(
    const float* __restrict__ coor, const float* __restrict__ region,
    const float* __restrict__ extents,
    const float* __restrict__ b1, const float* __restrict__ b2,
    const float* __restrict__ b3,
    const unsigned short* __restrict__ wsp,
    unsigned* __restrict__ pool) {
  __shared__ unsigned short X[128 * 128];   // 32KB bf16 acts (f32 funnel aliases)
  __shared__ unsigned short X5[128 * 40];   // 10KB input plane, row stride 80B
  __shared__ float reg_s[NM * TILE];        // 4KB
  const int tid = threadIdx.x;
  const int b = blockIdx.y;
  const int t0 = blockIdx.x * TILE;
  const int lane = tid & 63;
  const int wv = tid >> 6;                  // 0..7
  char* Xc = (char*)X;
  char* X5c = (char*)X5;

  {  // stage region tile: 8 rows x 128 (float2/thread)
    int m = tid >> 6, j = tid & 63;
    float2 v = *(const float2*)(region + ((size_t)b * NM + m) * PTS + t0 + j * 2);
    *(float2*)(reg_s + m * TILE + j * 2) = v;
  }
  {  // stage input plane X5[pt][k<32] bf16 (zeros for k>=5)
    const int pt = tid & 127;
    const int part = tid >> 7;  // 0..3 -> 16B chunk
    u16x8 hh = {0, 0, 0, 0, 0, 0, 0, 0};
    if (part == 0) {
      float e0 = extents[b * 3], e1 = extents[b * 3 + 1], e2 = extents[b * 3 + 2];
      float in5[5];
#pragma unroll
      for (int i = 0; i < 5; i++) in5[i] = coor[((size_t)b * 5 + i) * PTS + t0 + pt];
      in5[0] = (in5[0] - 0.5f) * e0;
      in5[1] = (in5[1] - 0.5f) * e1;
      in5[2] = (in5[2] - 0.5f) * e2;
#pragma unroll
      for (int q = 0; q < 5; q++) hh[q] = rbf(in5[q]);
    }
    *(u16x8*)(X5c + pt * 80 + part * 16) = hh;
  }
  __syncthreads();

  f32x4v acc[8];
  const int mt = wv;
  const int l15 = lane & 15, l4 = lane >> 4;

  {  // layer 1: single MFMA k-step (K=32, zero-padded)
    float4 bv = *(const float4*)(b1 + mt * 16 + l4 * 4);
    f32x4v b4; b4[0] = bv.x; b4[1] = bv.y; b4[2] = bv.z; b4[3] = bv.w;
#pragma unroll
    for (int nt = 0; nt < 8; nt++) acc[nt] = b4;
    bf16x8 ah = *(const bf16x8*)(wsp + ((mt * 4 + l4) * 16 + l15) * 8);
#pragma unroll
    for (int nt = 0; nt < 8; nt++) {
      bf16x8 bh = *(const bf16x8*)(X5c + (nt * 16 + l15) * 80 + l4 * 16);
      acc[nt] = __builtin_amdgcn_mfma_f32_16x16x32_bf16(ah, bh, acc[nt], 0, 0, 0);
    }
  }
  {  // leaky + round + write act1 to X
    const int ch0 = mt * 16 + l4 * 4;
#pragma unroll
    for (int nt = 0; nt < 8; nt++) {
      u16x4 h4;
#pragma unroll
      for (int r = 0; r < 4; r++) {
        float s = acc[nt][r];
        s = LEAKY(s);
        h4[r] = rbf(s);
      }
      int off = swzb(nt * 16 + l15, ch0 * 2);
      *(u16x4*)(Xc + off) = h4;
    }
  }
  __syncthreads();

  // layer 2
  mfmaLayer8s(wsp + 4096, b2, Xc, lane, mt, acc);
  __syncthreads();
  {  // leaky + round + write act2 back to X
    const int ch0 = mt * 16 + l4 * 4;
#pragma unroll
    for (int nt = 0; nt < 8; nt++) {
      u16x4 h4;
#pragma unroll
      for (int r = 0; r < 4; r++) {
        float s = acc[nt][r];
        s = LEAKY(s);
        h4[r] = rbf(s);
      }
      int off = swzb(nt * 16 + l15, ch0 * 2);
      *(u16x4*)(Xc + off) = h4;
    }
  }
  __syncthreads();
  // layer 3 (bias, no activation)
  mfmaLayer8s(wsp + 20480, b3, Xc, lane, mt, acc);
  __syncthreads();  // all X reads done; reuse X as f32 funnel

  {  // region-masked max -> funnel[c*8+m]
    float* funnel = (float*)X;
#pragma unroll
    for (int m = 0; m < NM; m++) {
      float rv[8];
#pragma unroll
      for (int nt = 0; nt < 8; nt++) rv[nt] = reg_s[m * TILE + nt * 16 + l15];
#pragma unroll
      for (int r = 0; r < 4; r++) {
        float mx = acc[0][r] * rv[0];
#pragma unroll
        for (int nt = 1; nt < 8; nt++) mx = fmaxf(mx, acc[nt][r] * rv[nt]);
        mx = fmaxf(mx, __shfl_xor(mx, 1));
        mx = fmaxf(mx, __shfl_xor(mx, 2));
        mx = fmaxf(mx, __shfl_xor(mx, 4));
        mx = fmaxf(mx, __shfl_xor(mx, 8));
        if (l15 == 0) funnel[(mt * 16 + l4 * 4 + r) * 8 + m] = mx;
      }
    }
  }
  __syncthreads();
  {  // order-independent pool: atomicMax of monotone-encoded f32 (2/thread)
    const float* fun = (const float*)X;
    unsigned* pl = pool + (size_t)b * 1024;
    atomicMax(pl + tid, encf(fun[tid]));
    atomicMax(pl + tid + 512, encf(fun[tid + 512]));
  }
}

// ============================================================
// Kernel C (o-split + fused softmax/sort): grid(512) 1-D, XCD-aware.
// id -> kt = (id&7)|((id>>7)<<3), bg = (id>>3)&7, og2 = (id>>6)&1.
// Block: 4 k x 64 o x 4 b x 8 m. Decodes pool -> softmax -> sorts its 4 k.
// As[16][260] + xsl 16KB -> 33KB LDS -> 4 blocks/CU.
// ============================================================
__global__ __launch_bounds__(256) void kC(const unsigned* __restrict__ pool,
                                          const float* __restrict__ w_sp,
                                          float* __restrict__ y32) {
  __shared__ float As[16 * 260];     // 16.6KB [cc][row = kk*64 + o', pad 4]
  __shared__ float xsl[4 * 128 * 8]; // 16KB  [bl][c][m]
  __shared__ int idxL[4][4][8];      // [bl][kk][r]
  const int tid = threadIdx.x;
  const int id = blockIdx.x;
  const int kt = (id & 7) | ((id >> 7) << 3);   // 0..31, same-kt -> same XCD
  const int bg = (id >> 3) & 7;                 // 0..7
  const int og2 = (id >> 6) & 1;                // 0..1
  const int k0 = kt * 4;
  const int o0 = og2 * 64;
  const int bbase = bg * 4;
  const int rg = tid & 63, cgq = tid >> 6;

  // decode pool (4 b x 1024) -> xsl
#pragma unroll
  for (int it = 0; it < 4; it++) {
    uint4 v = *(const uint4*)(pool + (size_t)(bbase + it) * 1024 + tid * 4);
    float4 f = {decf(v.x), decf(v.y), decf(v.z), decf(v.w)};
    *(float4*)(xsl + it * 1024 + tid * 4) = f;
  }
  // prologue: issue c0=0 staging loads (float4 = 4 k values)
  float4 wreg[4];
#pragma unroll
  for (int it = 0; it < 4; it++) {
    int q = tid + it * 256, o = q >> 4, cc = q & 15;
    wreg[it] = *(const float4*)(w_sp + (size_t)(o0 + o) * 16384 + (size_t)cc * 128 + k0);
  }
  __syncthreads();
  {  // softmax over c per (bl, m): 32 pairs x 8 threads
    int pair = tid >> 3, sub = tid & 7;
    int bl = pair >> 3, m = pair & 7;
    float* base = xsl + bl * 1024 + m;
    float v[16];
#pragma unroll
    for (int j = 0; j < 16; j++) v[j] = base[(sub + 8 * j) * 8];
    float mx = v[0];
#pragma unroll
    for (int j = 1; j < 16; j++) mx = fmaxf(mx, v[j]);
    mx = fmaxf(mx, __shfl_xor(mx, 1));
    mx = fmaxf(mx, __shfl_xor(mx, 2));
    mx = fmaxf(mx, __shfl_xor(mx, 4));
    float s = 0.f;
#pragma unroll
    for (int j = 0; j < 16; j++) { v[j] = expf(v[j] - mx); s += v[j]; }
    s += __shfl_xor(s, 1);
    s += __shfl_xor(s, 2);
    s += __shfl_xor(s, 4);
    float inv = 1.f / s;
#pragma unroll
    for (int j = 0; j < 16; j++) base[(sub + 8 * j) * 8] = v[j] * inv;
  }
  __syncthreads();
  if (tid < 16) {  // sort this block's 4 k-channels per batch
    int bl = tid >> 2, kk = tid & 3;
    float vv[8];
#pragma unroll
    for (int n = 0; n < 8; n++) vv[n] = xsl[bl * 1024 + (k0 + kk) * 8 + n];
    int used = 0;
#pragma unroll
    for (int n = 0; n < 8; n++) {
      int best = 0; float bv = -1.f;
#pragma unroll
      for (int q = 0; q < 8; q++) {
        bool ok = ((used >> q) & 1) == 0;
        if (ok && vv[q] > bv) { bv = vv[q]; best = q; }  // strict > == lowest-index tie-break
      }
      used |= 1 << best;
      idxL[bl][kk][n] = best;
    }
  }

  float acc[4][8];
#pragma unroll
  for (int i = 0; i < 4; i++)
#pragma unroll
    for (int j = 0; j < 8; j++) acc[i][j] = 0.f;

  for (int c0 = 0; c0 < 128; c0 += 16) {
    __syncthreads();
#pragma unroll
    for (int it = 0; it < 4; it++) {
      int q = tid + it * 256, o = q >> 4, cc = q & 15;
      As[cc * 260 + o]       = wreg[it].x;   // kk=0
      As[cc * 260 + 64 + o]  = wreg[it].y;   // kk=1
      As[cc * 260 + 128 + o] = wreg[it].z;   // kk=2
      As[cc * 260 + 192 + o] = wreg[it].w;   // kk=3
    }
    __syncthreads();
    if (c0 + 16 < 128) {  // prefetch next chunk (hidden under compute)
#pragma unroll
      for (int it = 0; it < 4; it++) {
        int q = tid + it * 256, o = q >> 4, cc = q & 15;
        wreg[it] = *(const float4*)(w_sp + (size_t)(o0 + o) * 16384 + (size_t)(c0 + 16 + cc) * 128 + k0);
      }
    }
#pragma unroll
    for (int cc = 0; cc < 16; cc++) {
      float4 a = *(const float4*)(As + cc * 260 + rg * 4);
      float4 p0 = *(const float4*)(xsl + cgq * 1024 + (c0 + cc) * 8);      // broadcast
      float4 p1 = *(const float4*)(xsl + cgq * 1024 + (c0 + cc) * 8 + 4);  // broadcast
      float av[4] = {a.x, a.y, a.z, a.w};
      float bv[8] = {p0.x, p0.y, p0.z, p0.w, p1.x, p1.y, p1.z, p1.w};
#pragma unroll
      for (int i = 0; i < 4; i++)
#pragma unroll
        for (int j = 0; j < 8; j++) acc[i][j] = fmaf(av[i], bv[j], acc[i][j]);
    }
  }
  // gather-sum epilogue: row = rg*4+i -> kk = rg>>4, o' = row&63.
  const int kk = rg >> 4;
  int ms[8];
#pragma unroll
  for (int r = 0; r < 8; r++) ms[r] = idxL[cgq][kk][r];
  float yp[4][8];
#pragma unroll
  for (int i4 = 0; i4 < 4; i4++) {
#pragma unroll
    for (int r = 0; r < 8; r++) {
      float v = 0.f;
#pragma unroll
      for (int j = 0; j < 8; j++) v += (j == ms[r]) ? acc[i4][j] : 0.f;
      yp[i4][r] = v;
    }
  }
#pragma unroll
  for (int i4 = 0; i4 < 4; i4++)
#pragma unroll
    for (int r = 0; r < 8; r++) {
      yp[i4][r] += __shfl_xor(yp[i4][r], 16);
      yp[i4][r] += __shfl_xor(yp[i4][r], 32);
    }
  if (rg < 16) {  // lane rg: o' = rg*4 + i4
    float* dst = y32 + ((size_t)(bbase + cgq) * 32 + kt) * 1024 + (size_t)(o0 + rg * 4) * 8;
#pragma unroll
    for (int i4 = 0; i4 < 4; i4++) {
      float4 v0 = {yp[i4][0], yp[i4][1], yp[i4][2], yp[i4][3]};
      float4 v1 = {yp[i4][4], yp[i4][5], yp[i4][6], yp[i4][7]};
      *(float4*)(dst + i4 * 8) = v0;
      *(float4*)(dst + i4 * 8 + 4) = v1;
    }
  }
}

// ============================================================
// Kernel Y: y[b][f] = leaky(sum_t y32[b][t][f] + b_sp[f>>3]). grid (4, B).
// ============================================================
__global__ __launch_bounds__(256) void kY(const float* __restrict__ y32,
                                          const float* __restrict__ b_sp,
                                          float* __restrict__ y) {
  int fg = blockIdx.x, b = blockIdx.y, tid = threadIdx.x;
  int f = fg * 256 + tid;
  const float* base = y32 + (size_t)b * 32768 + f;
  float s = 0.f;
#pragma unroll 8
  for (int t = 0; t < 32; t++) s += base[t * 1024];
  s += b_sp[f >> 3];
  y[(size_t)b * 1024 + f] = LEAKY(s);
}

// ============================================================
// Kernel E1: fc1 -> h1. grid (8, B), 256 thr; wave-per-output, coalesced rows.
// ============================================================
__global__ __launch_bounds__(256) void kE1(
    const float* __restrict__ y, const float* __restrict__ fc1_w,
    const float* __restrict__ fc1_b, float* __restrict__ h1) {
  int og = blockIdx.x, b = blockIdx.y, tid = threadIdx.x;
  int wid = tid >> 6, lane = tid & 63;
  const float4* yv = (const float4*)(y + (size_t)b * 1024);
  float4 u[4];
#pragma unroll
  for (int r = 0; r < 4; r++) u[r] = yv[r * 64 + lane];
#pragma unroll 4
  for (int pass = 0; pass < 16; pass++) {
    int o = og * 64 + pass * 4 + wid;
    const float4* wr = (const float4*)(fc1_w + (size_t)o * 1024);
    float sa = 0, sb = 0, sc = 0, sd = 0;
#pragma unroll
    for (int r = 0; r < 4; r++) {
      float4 wv = wr[r * 64 + lane];
      sa = fmaf(wv.x, u[r].x, sa); sb = fmaf(wv.y, u[r].y, sb);
      sc = fmaf(wv.z, u[r].z, sc); sd = fmaf(wv.w, u[r].w, sd);
    }
    float s = (sa + sb) + (sc + sd);
#pragma unroll
    for (int d = 1; d < 64; d <<= 1) s += __shfl_xor(s, d);
    if (lane == 0) {
      float t = s + fc1_b[o];
      h1[(size_t)b * 512 + o] = LEAKY(t);
    }
  }
}

// ============================================================
// Kernel E2: fc2 -> heads. grid (B), 1024 thr (16 waves).
// ============================================================
__global__ __launch_bounds__(1024) void kE2(
    const float* __restrict__ h1, const float* __restrict__ fc2_w,
    const float* __restrict__ fc2_b,
    const float* __restrict__ fcr_w, const float* __restrict__ fcr_b,
    const float* __restrict__ fct_w, const float* __restrict__ fct_b,
    float* __restrict__ out) {
  __shared__ float h1l[512];
  __shared__ float h2[256];
  int b = blockIdx.x, tid = threadIdx.x;
  int w = tid >> 6, lane = tid & 63;
  if (tid < 128) {
    float4 v = ((const float4*)(h1 + (size_t)b * 512))[tid];
    ((float4*)h1l)[tid] = v;
  }
  __syncthreads();
  {  // fc2: 16 waves x 16 outputs, coalesced rows
    const float4* h1v = (const float4*)h1l;
    float4 u0 = h1v[lane], u1 = h1v[64 + lane];
#pragma unroll 2
    for (int pass = 0; pass < 16; pass++) {
      int o = w * 16 + pass;
      const float4* wr = (const float4*)(fc2_w + (size_t)o * 512);
      float4 w0 = wr[lane], w1 = wr[64 + lane];
      float sa = fmaf(w0.x, u0.x, 0.f), sb = fmaf(w0.y, u0.y, 0.f);
      float sc = fmaf(w0.z, u0.z, 0.f), sd = fmaf(w0.w, u0.w, 0.f);
      sa = fmaf(w1.x, u1.x, sa); sb = fmaf(w1.y, u1.y, sb);
      sc = fmaf(w1.z, u1.z, sc); sd = fmaf(w1.w, u1.w, sd);
      float s = (sa + sb) + (sc + sd);
#pragma unroll
      for (int d = 1; d < 64; d <<= 1) s += __shfl_xor(s, d);
      if (lane == 0) {
        float t = s + fc2_b[o];
        h2[o] = LEAKY(t);
      }
    }
  }
  __syncthreads();
  if (w < 7) {  // heads: wave-per-output
    bool isrot = w < 4;
    int o = isrot ? w : w - 4;
    const float4* wr = (const float4*)((isrot ? fcr_w : fct_w) + (size_t)o * 256);
    const float4* uv = (const float4*)h2;
    float4 wv = wr[lane];
    float4 u = uv[lane];
    float s = fmaf(wv.x, u.x, fmaf(wv.y, u.y, fmaf(wv.z, u.z, wv.w * u.w)));
#pragma unroll
    for (int d = 1; d < 64; d <<= 1) s += __shfl_xor(s, d);
    if (lane == 0) {
      float t = s + (isrot ? fcr_b[o] : fct_b[o]);
      out[isrot ? (b * 4 + o) : (128 + b * 3 + o)] = t;
    }
  }
}

extern "C" void kernel_launch(void* const* d_in, const int* in_sizes, int n_in,
                              void* d_out, int out_size, void* d_ws, size_t ws_size,
                              hipStream_t stream) {
  const float* coor    = (const float*)d_in[0];
  const float* region  = (const float*)d_in[1];
  const float* extents = (const float*)d_in[2];
  const float* w1 = (const float*)d_in[3];  const float* b1 = (const float*)d_in[4];
  const float* w2 = (const float*)d_in[5];  const float* b2 = (const float*)d_in[6];
  const float* w3 = (const float*)d_in[7];  const float* b3 = (const float*)d_in[8];
  const float* w_sp = (const float*)d_in[9];  const float* b_sp = (const float*)d_in[10];
  const float* fc1_w = (const float*)d_in[11]; const float* fc1_b = (const float*)d_in[12];
  const float* fc2_w = (const float*)d_in[13]; const float* fc2_b = (const float*)d_in[14];
  const float* fcr_w = (const float*)d_in[15]; const float* fcr_b = (const float*)d_in[16];
  const float* fct_w = (const float*)d_in[17]; const float* fct_b = (const float*)d_in[18];

  char* ws = (char*)d_ws;
  unsigned* pool = (unsigned*)(ws + OFF_POOL);
  unsigned short* wsp = (unsigned short*)(ws + OFF_WSP);
  float* y32  = (float*)(ws + OFF_Y32);
  float* y    = (float*)(ws + OFF_Y);
  float* h1   = (float*)(ws + OFF_H1);
  float* out  = (float*)d_out;

  kW<<<dim3(128), 256, 0, stream>>>(w1, w2, w3, wsp, pool);
  kA<<<dim3(NTILES, NBATCH), 512, 0, stream>>>(coor, region, extents,
                                               b1, b2, b3, wsp, pool);
  kC<<<dim3(512), 256, 0, stream>>>(pool, w_sp, y32);
  kY<<<dim3(4, NBATCH), 256, 0, stream>>>(y32, b_sp, y);
  kE1<<<dim3(8, NBATCH), 256, 0, stream>>>(y, fc1_w, fc1_b, h1);
  kE2<<<dim3(NBATCH), 1024, 0, stream>>>(h1, fc2_w, fc2_b, fcr_w, fcr_b,
                                         fct_w, fct_b, out);
}